// Round 5
// baseline (364.697 us; speedup 1.0000x reference)
//
#include <hip/hip_runtime.h>

#define NB 4
#define NC 2
#define ND 160
#define NH 160
#define NW 160
#define NG 8
#define HWSZ (NH * NW)              // 25,600
#define DHW (ND * HWSZ)             // 4,096,000
#define NTHR 256
#define NBLOCKS 32000               // 4 b * 160 d * 50 tile-groups (div by 8)
#define BLK_PER_B 8000              // 160 * 50
#define BLK_PER_D 50
#define TILES_X 5                   // 160 / 32

// vectors with relaxed alignment (dword-aligned global loads are legal)
typedef float v2f __attribute__((ext_vector_type(2), aligned(4)));
typedef float v4fa __attribute__((ext_vector_type(4), aligned(4)));

// Single-fold mirror reflect into [0,159], period 318. Exact for |t| <= 318;
// here |t| <= ~177 (|u|*79.5 <= ~17 for this dataset). Branchless.
__device__ __forceinline__ float reflect_mirror(float t) {
    t = fabsf(t);
    return fminf(t, 318.0f - t);
}

__device__ __forceinline__ float lerp2(const float* __restrict__ p, float g) {
    float a = p[0], b = p[1];
    return a + (b - a) * g;
}

__global__ __launch_bounds__(256) void elastic_deform_kernel(
    const float* __restrict__ x,      // [B,C,D,H,W]
    const float* __restrict__ flow,   // [B,3,G,G,G]
    float* __restrict__ out)          // [B,C,D,H,W]
{
    // XCD chunk swizzle (L2 locality)
    int bid = blockIdx.x;
    int eff = (bid & 7) * (NBLOCKS / 8) + (bid >> 3);

    int b  = eff / BLK_PER_B;
    int e2 = eff - b * BLK_PER_B;
    int d  = e2 / BLK_PER_D;
    int e3 = e2 - d * BLK_PER_D;               // tile-group in slice [0,50)

    // wave = 32x4 (w x h) tile; each lane owns TWO adjacent voxels (w0, w0+1).
    // One dwordx4 per corner row serves both voxels' x-lerps -> half the
    // gather addresses per output (TA address throughput is the R4 wall).
    int wid  = (int)threadIdx.x >> 6;
    int lane = (int)threadIdx.x & 63;
    int tslice = e3 * 4 + wid;                 // [0,200)
    int ty = tslice / TILES_X;                 // [0,40)
    int tx = tslice - ty * TILES_X;            // [0,5)
    int h  = ty * 4 + (lane >> 4);
    int w0 = tx * 32 + (lane & 15) * 2;

    const float s = 7.0f / 159.0f;

    // ---- z-reduction of coarse flow is block-uniform: once into LDS.
    float cz  = (float)d * s;
    int   izb = min((int)cz, NG - 2);
    float fz  = cz - (float)izb;

    __shared__ float sfz[3 * 64];              // [ch][gy*8+gx], 768 B
    if (threadIdx.x < 192) {
        int ch = (int)threadIdx.x >> 6;
        int yx = (int)threadIdx.x & 63;
        const float* fp = flow + ((b * 3 + ch) * NG + izb) * 64 + yx;
        float f0 = fp[0], f1 = fp[64];
        sfz[ch * 64 + yx] = f0 + (f1 - f0) * fz;
    }
    __syncthreads();

    // ---- coarse-flow: y-reduce at 3 x-nodes (covers both voxels' ixb)
    float cy = (float)h * s;
    int iyb = min((int)cy, NG - 2); float fy = cy - (float)iyb;
    float cx0 = (float)w0 * s;
    int ixa = min((int)cx0, NG - 2);
    float e[3][3];
#pragma unroll
    for (int ch = 0; ch < 3; ++ch) {
        const float* p = sfz + ch * 64 + iyb * NG;
#pragma unroll
        for (int j = 0; j < 3; ++j) {
            int ix = (j == 2) ? min(ixa + 2, NG - 1) : (ixa + j);
            float f0 = p[ix], f1 = p[NG + ix];
            e[ch][j] = f0 + (f1 - f0) * fy;
        }
    }

    // ---- per-voxel displaced coords
    int xb[2], yb[2], zb[2];
    float sxv[2], gy[2], gz[2];
#pragma unroll
    for (int i = 0; i < 2; ++i) {
        float cx = cx0 + (float)i * s;
        int ixb = min((int)cx, NG - 2);
        int oi  = ixb - ixa;                    // 0 or 1
        float fx = cx - (float)ixb;
        float s0, s1;
        s0 = oi ? e[0][1] : e[0][0];  s1 = oi ? e[0][2] : e[0][1];
        float ux = s0 + (s1 - s0) * fx;
        s0 = oi ? e[1][1] : e[1][0];  s1 = oi ? e[1][2] : e[1][1];
        float uy = s0 + (s1 - s0) * fx;
        s0 = oi ? e[2][1] : e[2][0];  s1 = oi ? e[2][2] : e[2][1];
        float uz = s0 + (s1 - s0) * fx;

        float sx = reflect_mirror((float)(w0 + i) + ux * 79.5f);
        float sy = reflect_mirror((float)h + uy * 79.5f);
        float sz = reflect_mirror((float)d + uz * 79.5f);
        xb[i] = min((int)sx, NW - 2); sxv[i] = sx;
        yb[i] = min((int)sy, NH - 2); gy[i] = sy - (float)yb[i];
        zb[i] = min((int)sz, ND - 2); gz[i] = sz - (float)zb[i];
    }

    // shared 4-wide window: base xq (clamped so xq+3 <= 159: never leaves row)
    int xq = min(xb[0], NW - 4);
    const float* basep = x + (size_t)b * (NC * DHW);
    const float* p0 = basep + (zb[0] * NH + yb[0]) * NW + xq;   // ch0
    const float* p1 = p0 + DHW;                                  // ch1

    v4fa qa0 = *(const v4fa*)(p0);
    v4fa qa1 = *(const v4fa*)(p0 + NW);
    v4fa qa2 = *(const v4fa*)(p0 + HWSZ);
    v4fa qa3 = *(const v4fa*)(p0 + HWSZ + NW);
    v4fa qb0 = *(const v4fa*)(p1);
    v4fa qb1 = *(const v4fa*)(p1 + NW);
    v4fa qb2 = *(const v4fa*)(p1 + HWSZ);
    v4fa qb3 = *(const v4fa*)(p1 + HWSZ + NW);

    // branchless piecewise-linear eval inside the 4-vector:
    // val = q.x + m1*(q.y-q.x) + m2*(q.z-q.y) + m3*(q.w-q.z),
    // mk = clamp(pos-(k-1), 0, 1), pos = sx - xq  (exact for pos in [0,3])
    float posA = sxv[0] - (float)xq;
    float A1 = fminf(posA, 1.0f);
    float A2 = fminf(fmaxf(posA - 1.0f, 0.0f), 1.0f);
    float A3 = fminf(fmaxf(posA - 2.0f, 0.0f), 1.0f);
    float posB = sxv[1] - (float)xq;
    float B1 = fminf(posB, 1.0f);
    float B2 = fminf(fmaxf(posB - 1.0f, 0.0f), 1.0f);
    float B3 = fminf(fmaxf(posB - 2.0f, 0.0f), 1.0f);

#define PWL(q, m1, m2, m3) \
    ((q).x + (m1) * ((q).y - (q).x) + (m2) * ((q).z - (q).y) + (m3) * ((q).w - (q).z))

    // voxel0 (always valid: xb[0]-xq in {0,1,2})
    float r0c0, r0c1;
    {
        float a0 = PWL(qa0, A1, A2, A3) + (PWL(qa1, A1, A2, A3) - PWL(qa0, A1, A2, A3)) * gy[0];
        float a1 = PWL(qa2, A1, A2, A3) + (PWL(qa3, A1, A2, A3) - PWL(qa2, A1, A2, A3)) * gy[0];
        r0c0 = a0 + (a1 - a0) * gz[0];
        float b0 = PWL(qb0, A1, A2, A3) + (PWL(qb1, A1, A2, A3) - PWL(qb0, A1, A2, A3)) * gy[0];
        float b1 = PWL(qb2, A1, A2, A3) + (PWL(qb3, A1, A2, A3) - PWL(qb2, A1, A2, A3)) * gy[0];
        r0c1 = b0 + (b1 - b0) * gz[0];
    }

    // voxel1 shared path (valid iff same rows and window covers it)
    float r1c0, r1c1;
    {
        float a0 = PWL(qa0, B1, B2, B3) + (PWL(qa1, B1, B2, B3) - PWL(qa0, B1, B2, B3)) * gy[1];
        float a1 = PWL(qa2, B1, B2, B3) + (PWL(qa3, B1, B2, B3) - PWL(qa2, B1, B2, B3)) * gy[1];
        r1c0 = a0 + (a1 - a0) * gz[1];
        float b0 = PWL(qb0, B1, B2, B3) + (PWL(qb1, B1, B2, B3) - PWL(qb0, B1, B2, B3)) * gy[1];
        float b1 = PWL(qb2, B1, B2, B3) + (PWL(qb3, B1, B2, B3) - PWL(qb2, B1, B2, B3)) * gy[1];
        r1c1 = b0 + (b1 - b0) * gz[1];
    }

    // repair: voxel1 straddles a (z,y) row boundary or leaves the window
    // (~36% of lanes; masked-off lanes issue no TA requests)
    bool rep = (zb[1] != zb[0]) | (yb[1] != yb[0]) |
               ((unsigned)(xb[1] - xq) > 2u);
    if (rep) {
        float gx1 = sxv[1] - (float)xb[1];
        const float* t0 = basep + (zb[1] * NH + yb[1]) * NW + xb[1];
        const float* t1 = t0 + DHW;
        {
            float v00 = lerp2(t0, gx1);
            float v01 = lerp2(t0 + NW, gx1);
            float v10 = lerp2(t0 + HWSZ, gx1);
            float v11 = lerp2(t0 + HWSZ + NW, gx1);
            float a0 = v00 + (v01 - v00) * gy[1];
            float a1 = v10 + (v11 - v10) * gy[1];
            r1c0 = a0 + (a1 - a0) * gz[1];
        }
        {
            float v00 = lerp2(t1, gx1);
            float v01 = lerp2(t1 + NW, gx1);
            float v10 = lerp2(t1 + HWSZ, gx1);
            float v11 = lerp2(t1 + HWSZ + NW, gx1);
            float a0 = v00 + (v01 - v00) * gy[1];
            float a1 = v10 + (v11 - v10) * gy[1];
            r1c1 = a0 + (a1 - a0) * gz[1];
        }
    }

    // stores: 16-lane row-group covers 32 voxels * 4B = 128B = full lines
    size_t opos = (size_t)b * (NC * DHW) + (size_t)(d * NH + h) * NW + w0;
    v2f o0 = { r0c0, r1c0 };
    v2f o1 = { r0c1, r1c1 };
    __builtin_nontemporal_store(o0, (v2f*)(out + opos));
    __builtin_nontemporal_store(o1, (v2f*)(out + opos + DHW));
}

extern "C" void kernel_launch(void* const* d_in, const int* in_sizes, int n_in,
                              void* d_out, int out_size, void* d_ws, size_t ws_size,
                              hipStream_t stream) {
    const float* x    = (const float*)d_in[0];
    const float* flow = (const float*)d_in[1];
    float* out = (float*)d_out;
    elastic_deform_kernel<<<NBLOCKS, NTHR, 0, stream>>>(x, flow, out);
}

// Round 6
// 338.264 us; speedup vs baseline: 1.0781x; 1.0781x over previous
//
#include <hip/hip_runtime.h>

#define NB 4
#define NC 2
#define ND 160
#define NH 160
#define NW 160
#define NG 8
#define HWSZ (NH * NW)              // 25,600
#define DHW (ND * HWSZ)             // 4,096,000
#define NTHR 256
#define NBLOCKS (NB * DHW / NTHR)   // 64,000  (divisible by 8 -> XCD swizzle ok)
#define BLK_PER_B (DHW / NTHR)      // 16,000  (block never straddles b)
#define BLK_PER_D (HWSZ / NTHR)     // 100     (block never straddles d)
#define TILES_X 10                  // 160 / 16

// 8B vector, 4B-aligned (legal widest load without alignment UB)
typedef float v2f __attribute__((ext_vector_type(2), aligned(4)));

// Single-fold mirror reflect into [0,159], period 318. Exact for |t| <= 318;
// here |t| <= ~177 (|u|*79.5 <= ~17 for this dataset). Branchless.
__device__ __forceinline__ float reflect_mirror(float t) {
    t = fabsf(t);
    return fminf(t, 318.0f - t);
}

__device__ __forceinline__ float lerp_v(v2f q, float g) {
    return q.x + (q.y - q.x) * g;
}

__global__ __launch_bounds__(256) void elastic_deform_kernel(
    const float* __restrict__ x,      // [B,C,D,H,W]
    const float* __restrict__ flow,   // [B,3,G,G,G]
    float* __restrict__ out)          // [B,C,D,H,W]
{
    // XCD chunk swizzle: consecutive eff -> same XCD (L2 locality)
    int bid = blockIdx.x;
    int eff = (bid & 7) * (NBLOCKS / 8) + (bid >> 3);

    // b, d block-uniform -> scalar regs
    int b  = eff / BLK_PER_B;
    int e2 = eff - b * BLK_PER_B;
    int d  = e2 / BLK_PER_D;
    int e3 = e2 - d * BLK_PER_D;

    // wave = one 16x4 (w x h) tile; one voxel per lane (R4 structure: the
    // measured TA floor -- 8.2 lines/gather vs the 8-line packing minimum).
    // Pairing/repair schemes (R5) are falsified: masked repair re-adds the
    // 16-cyc per-instruction base cost that sharing removes.
    int wid  = (int)threadIdx.x >> 6;          // wave id in block [0,4)
    int lane = (int)threadIdx.x & 63;
    int tslice = e3 * 4 + wid;                 // tile id in slice [0,400)
    int ty = tslice / TILES_X;                 // [0,40)
    int tx = tslice - ty * TILES_X;            // [0,10)
    int h  = ty * 4 + (lane >> 4);             // 4 rows per tile
    int w  = tx * 16 + (lane & 15);            // 16 cols per tile (64B aligned)

    const float s = 7.0f / 159.0f;

    // ---- z-reduction of coarse flow is block-uniform: once into LDS.
    float cz  = (float)d * s;
    int   izb = min((int)cz, NG - 2);
    float fz  = cz - (float)izb;

    __shared__ float sfz[3 * 64];           // [ch][gy*8+gx], 768 B
    if (threadIdx.x < 192) {
        int ch = (int)threadIdx.x >> 6;
        int yx = (int)threadIdx.x & 63;
        const float* fp = flow + ((b * 3 + ch) * NG + izb) * 64 + yx;
        float f0 = fp[0], f1 = fp[64];      // planes izb, izb+1
        sfz[ch * 64 + yx] = f0 + (f1 - f0) * fz;
    }
    __syncthreads();

    // ---- per-thread coarse-flow bilinear (y,x) from the z-reduced table
    float cy = (float)h * s;
    float cx = (float)w * s;
    int iyb = min((int)cy, NG - 2); float fy = cy - (float)iyb;
    int ixb = min((int)cx, NG - 2); float fx = cx - (float)ixb;
    int cpos = iyb * NG + ixb;

    float u[3];
#pragma unroll
    for (int ch = 0; ch < 3; ++ch) {
        const float* p = sfz + ch * 64 + cpos;
        float f00 = p[0], f01 = p[1], f10 = p[8], f11 = p[9];
        float a0 = f00 + (f01 - f00) * fx;
        float a1 = f10 + (f11 - f10) * fx;
        u[ch] = a0 + (a1 - a0) * fy;
    }

    // ---- sample coords
    float sx = reflect_mirror((float)w + u[0] * 79.5f);
    float sy = reflect_mirror((float)h + u[1] * 79.5f);
    float sz = reflect_mirror((float)d + u[2] * 79.5f);

    int xb = min((int)sx, NW - 2); float gx = sx - (float)xb;
    int yb = min((int)sy, NH - 2); float gy = sy - (float)yb;
    int zb = min((int)sz, ND - 2); float gz = sz - (float)zb;

    int off = (zb * NH + yb) * NW + xb;
    const float* p0 = x + (size_t)b * (NC * DHW) + off;   // ch0
    const float* p1 = p0 + DHW;                           // ch1

    // plain loads, no fence (R3: compiler's own pipelining is already right)
    float r0, r1;
    {
        float v00 = lerp_v(*(const v2f*)(p0), gx);
        float v01 = lerp_v(*(const v2f*)(p0 + NW), gx);
        float v10 = lerp_v(*(const v2f*)(p0 + HWSZ), gx);
        float v11 = lerp_v(*(const v2f*)(p0 + HWSZ + NW), gx);
        float a0 = v00 + (v01 - v00) * gy;
        float a1 = v10 + (v11 - v10) * gy;
        r0 = a0 + (a1 - a0) * gz;
    }
    {
        float v00 = lerp_v(*(const v2f*)(p1), gx);
        float v01 = lerp_v(*(const v2f*)(p1 + NW), gx);
        float v10 = lerp_v(*(const v2f*)(p1 + HWSZ), gx);
        float v11 = lerp_v(*(const v2f*)(p1 + HWSZ + NW), gx);
        float a0 = v00 + (v01 - v00) * gy;
        float a1 = v10 + (v11 - v10) * gy;
        r1 = a0 + (a1 - a0) * gz;
    }

    // stores: CACHED (not NT). The 4 waves of a block write x-adjacent 64B
    // halves of the same lines; L2 write-back merges them to full lines
    // (R4's NT half-line segments amplified WRITE_SIZE 128->144 MB).
    size_t opos = (size_t)b * (NC * DHW) + (size_t)(d * NH + h) * NW + w;
    out[opos] = r0;
    out[opos + DHW] = r1;
}

extern "C" void kernel_launch(void* const* d_in, const int* in_sizes, int n_in,
                              void* d_out, int out_size, void* d_ws, size_t ws_size,
                              hipStream_t stream) {
    const float* x    = (const float*)d_in[0];
    const float* flow = (const float*)d_in[1];
    float* out = (float*)d_out;
    elastic_deform_kernel<<<NBLOCKS, NTHR, 0, stream>>>(x, flow, out);
}